// Round 5
// baseline (203.633 us; speedup 1.0000x reference)
//
#include <hip/hip_runtime.h>

#define NFRAMES 3749   // (960000-512)/256 + 1
#define NBLOCKS 3750   // 256-sample hop blocks per batch (960000/256)
#define NSAMP   960000
#define NBATCH  32
#define NWORDS  59     // ceil(3750/64) -> covers bit index up to 3775 (incl. e==NFRAMES)
#define SILENCE_FRAMES 18
#define MIN_SPEECH_FRAMES 6
#define MAXSEG  256    // true bound: 1 + floor(3748/19) = 198
#define NT      512    // vad_finish block size (8 waves)

// Kernel A: fp64 sums of fp32 squares per 256-sample hop block. (unchanged, ~HBM-bound)
__global__ __launch_bounds__(256) void vad_block_sums(const float* __restrict__ wav,
                                                      double* __restrict__ bs) {
    int tid = threadIdx.x;
    const float* p = wav + (size_t)blockIdx.x * 4096 + tid * 16;
    double acc = 0.0;
    #pragma unroll
    for (int i = 0; i < 4; ++i) {
        float4 v = *(const float4*)(p + i * 4);
        acc += (double)(v.x * v.x);
        acc += (double)(v.y * v.y);
        acc += (double)(v.z * v.z);
        acc += (double)(v.w * v.w);
    }
    #pragma unroll
    for (int m = 1; m < 16; m <<= 1)
        acc += __shfl_xor(acc, m, 64);
    if ((tid & 15) == 0)
        bs[(size_t)blockIdx.x * 16 + (tid >> 4)] = acc;
}

// Kernel B: one block per batch, 512 threads. Energies live in registers
// (ub[8], frame t = tid + 512*i). Quantile via 2-bit bisection (16 steps,
// no LDS atomics). Mask ballots formed straight from registers. Segment
// extraction via windowed bit ops + shfl scans.
__global__ __launch_bounds__(NT) void vad_finish(const double* __restrict__ bs,
                                                 int* __restrict__ out) {
    __shared__ unsigned long long mw[NWORDS];   // mask bits
    __shared__ unsigned long long sw[NWORDS];   // segment-start bits
    __shared__ unsigned long long lw[NWORDS];   // segment-last-one bits
    __shared__ unsigned long long Sw[NWORDS];   // valid-segment start markers
    __shared__ unsigned long long Ew[NWORDS];   // valid-segment end markers
    __shared__ int wbS[NWORDS], wbL[NWORDS];    // word-prefix bit counts
    __shared__ int startpos[MAXSEG], lastpos[MAXSEG];
    __shared__ int zc[8];                       // per-wave zero counts
    __shared__ int r01[2][8], r2[2][8];         // bisect reduce slots (dbuf)
    __shared__ int cle[8];                      // derive: count <= vb per wave
    __shared__ unsigned mgt[8];                 // derive: min > vb per wave
    __shared__ int nseg_sh;

    int b = blockIdx.x;
    int tid = threadIdx.x;
    int lane = tid & 63, wv = tid >> 6;
    const double* row = bs + (size_t)b * NBLOCKS;

    // Phase 1: energies (exact fp64 sum -> single fp32 rounding) into registers.
    unsigned ub[8];
    int nel = 0, myzero = 0;
    #pragma unroll
    for (int i = 0; i < 8; ++i) {
        int t = tid + (i << 9);
        if (t < NFRAMES) {
            double s = row[t] + row[t + 1];
            float e = (float)(s * (1.0 / 512.0));
            ub[i] = __float_as_uint(e);
            ++nel;
            if (e <= 0.0f) ++myzero;
        } else {
            ub[i] = 0u;
        }
    }
    int z = myzero;
    #pragma unroll
    for (int off = 32; off; off >>= 1) z += __shfl_xor(z, off, 64);
    if (lane == 0) zc[wv] = z;
    __syncthreads();
    int nzero = 0;
    #pragma unroll
    for (int i = 0; i < 8; ++i) nzero += zc[i];
    int nz = NFRAMES - nzero;   // uniform

    // Phase 2: threshold. Positive fp32 bit patterns order identically to floats.
    float thr;
    if (nz > 0) {   // block-uniform
        float pos = 0.2f * (float)(nz - 1);
        int lo = (int)floorf(pos), hi = (int)ceilf(pos);
        int rank_lo = min(max(nzero + lo, 0), NFRAMES - 1);
        int rank_hi = min(max(nzero + hi, 0), NFRAMES - 1);

        // 2-bit-per-step bisection for s[rank_lo]; decisions are uniform.
        unsigned base = 0u;
        int k = rank_lo;
        for (int step = 15; step >= 0; --step) {
            int shift = step << 1;
            int par = step & 1;
            int c0 = 0, c1 = 0, c2 = 0;
            for (int j = 0; j < nel; ++j) {
                unsigned u = ub[j];
                bool match = (((u ^ base) >> shift) >> 2) == 0u;  // high bits equal
                unsigned d = (u >> shift) & 3u;
                if (match) {
                    c0 += (d == 0u);
                    c1 += (d == 1u);
                    c2 += (d == 2u);
                }
            }
            int p01 = c0 | (c1 << 16);
            #pragma unroll
            for (int off = 32; off; off >>= 1) {
                p01 += __shfl_xor(p01, off, 64);
                c2  += __shfl_xor(c2, off, 64);
            }
            if (lane == 0) { r01[par][wv] = p01; r2[par][wv] = c2; }
            __syncthreads();
            int C0 = 0, C1 = 0, C2 = 0;
            #pragma unroll
            for (int i = 0; i < 8; ++i) {
                int v = r01[par][i];
                C0 += v & 0xFFFF;
                C1 += v >> 16;
                C2 += r2[par][i];
            }
            unsigned d;
            if (k < C0)                 { d = 0u; }
            else if (k < C0 + C1)       { d = 1u; k -= C0; }
            else if (k < C0 + C1 + C2)  { d = 2u; k -= C0 + C1; }
            else                        { d = 3u; k -= C0 + C1 + C2; }
            base |= d << shift;
        }
        unsigned vb = base;            // bits of s[rank_lo]
        float vlo = __uint_as_float(vb), vhi;

        if (rank_hi != rank_lo) {      // uniform: derive s[rank_lo+1]
            int c = 0;
            unsigned mg = 0xFFFFFFFFu;
            for (int j = 0; j < nel; ++j) {
                unsigned u = ub[j];
                if (u <= vb) ++c;
                else mg = min(mg, u);
            }
            #pragma unroll
            for (int off = 32; off; off >>= 1) {
                c += __shfl_xor(c, off, 64);
                unsigned o = (unsigned)__shfl_xor((int)mg, off, 64);
                mg = min(mg, o);
            }
            if (lane == 0) { cle[wv] = c; mgt[wv] = mg; }
            __syncthreads();
            int C = 0;
            unsigned MG = 0xFFFFFFFFu;
            #pragma unroll
            for (int i = 0; i < 8; ++i) { C += cle[i]; MG = min(MG, mgt[i]); }
            vhi = (C >= rank_lo + 2) ? vlo : __uint_as_float(MG);
        } else {
            vhi = vlo;
        }
        float frac = pos - (float)lo;
        thr = vlo * (1.0f - frac) + vhi * frac;   // fp32, exactly as reference
    } else {
        thr = 0.01f;
    }

    // Phase 5: mask bit-words, ballots straight from registers.
    // t = tid + 512*i  =>  word = 8*i + wv, bit = lane.
    #pragma unroll
    for (int i = 0; i < 8; ++i) {
        int t = tid + (i << 9);
        bool p = (t < NFRAMES) && (__uint_as_float(ub[i]) > thr);
        unsigned long long bm = __ballot(p);
        int w = (i << 3) + wv;
        if (lane == 0 && w < NWORDS) mw[w] = bm;
    }
    __syncthreads();

    // Phase 6: segment starts (no 1 in prev 18) / last-ones (no 1 in next 18)
    for (int wi = wv; wi < NWORDS; wi += 8) {
        unsigned long long W  = mw[wi];
        unsigned long long Wm = (wi > 0) ? mw[wi - 1] : 0ull;
        unsigned long long Wp = (wi + 1 < NWORDS) ? mw[wi + 1] : 0ull;
        int l = lane;
        bool mt = (W >> l) & 1ull;
        bool prev_any, next_any;
        if (l >= 18) {
            prev_any = ((W >> (l - 18)) & 0x3FFFFull) != 0ull;
        } else {
            unsigned long long lowpart = W & ((1ull << l) - 1ull);   // bits t-l..t-1
            unsigned long long hipart  = Wm >> (46 + l);             // 18-l bits
            prev_any = (lowpart | hipart) != 0ull;
        }
        if (l <= 45) {
            next_any = ((W >> (l + 1)) & 0x3FFFFull) != 0ull;
        } else {
            unsigned long long a  = (l < 63) ? (W >> (l + 1)) : 0ull;     // 63-l bits
            unsigned long long bb = Wp & ((1ull << (l - 45)) - 1ull);      // l-45 bits
            next_any = (a | bb) != 0ull;
        }
        unsigned long long bS = __ballot(mt && !prev_any);
        unsigned long long bL = __ballot(mt && !next_any);
        if (lane == 0) { sw[wi] = bS; lw[wi] = bL; }
    }
    __syncthreads();

    // Phase 7: word-prefix counts of starts/lasts via wave-0 shfl scan
    if (tid < 64) {
        unsigned long long wS = (tid < NWORDS) ? sw[tid] : 0ull;
        unsigned long long wL = (tid < NWORDS) ? lw[tid] : 0ull;
        int pS = __popcll(wS), pL = __popcll(wL);
        int iS = pS, iL = pL;
        #pragma unroll
        for (int off = 1; off < 64; off <<= 1) {
            int a = __shfl_up(iS, off, 64);
            int c = __shfl_up(iL, off, 64);
            if (lane >= off) { iS += a; iL += c; }
        }
        if (tid < NWORDS) { wbS[tid] = iS - pS; wbL[tid] = iL - pL; }
        if (tid == 63) nseg_sh = iS;
    }
    __syncthreads();

    // Phase 8: scatter ordered start/last positions; clear S/E marker words
    for (int wi = wv; wi < NWORDS; wi += 8) {
        unsigned long long wS = sw[wi], wL = lw[wi];
        int t = (wi << 6) + lane;
        unsigned long long lmask = (1ull << lane) - 1ull;
        if ((wS >> lane) & 1ull) startpos[wbS[wi] + __popcll(wS & lmask)] = t;
        if ((wL >> lane) & 1ull) lastpos[wbL[wi] + __popcll(wL & lmask)] = t;
    }
    for (int wi = tid; wi < NWORDS; wi += NT) { Sw[wi] = 0ull; Ew[wi] = 0ull; }
    __syncthreads();

    // Phase 9: per segment: end = L (closed) or n (open, L >= n-18); validity
    int nseg = nseg_sh;
    for (int k2 = tid; k2 < nseg; k2 += NT) {
        int s = startpos[k2], L = lastpos[k2];
        int e = (L >= NFRAMES - SILENCE_FRAMES) ? NFRAMES : L;
        if (e - s >= MIN_SPEECH_FRAMES) {
            atomicOr(&Sw[s >> 6], 1ull << (s & 63));
            atomicOr(&Ew[e >> 6], 1ull << (e & 63));
        }
    }
    __syncthreads();

    // Phase 10: word-prefix counts of S/E markers (reuse wbS/wbL)
    if (tid < 64) {
        unsigned long long wS = (tid < NWORDS) ? Sw[tid] : 0ull;
        unsigned long long wE = (tid < NWORDS) ? Ew[tid] : 0ull;
        int pS = __popcll(wS), pE = __popcll(wE);
        int iS = pS, iE = pE;
        #pragma unroll
        for (int off = 1; off < 64; off <<= 1) {
            int a = __shfl_up(iS, off, 64);
            int c = __shfl_up(iE, off, 64);
            if (lane >= off) { iS += a; iE += c; }
        }
        if (tid < NWORDS) { wbS[tid] = iS - pS; wbL[tid] = iE - pE; }
    }
    __syncthreads();

    // Phase 11: coverage = (#starts <= t) > (#ends <= t); write int32 output
    int* orow = out + (size_t)b * NFRAMES;
    for (int wi = wv; wi < NWORDS; wi += 8) {
        unsigned long long wS2 = Sw[wi], wE2 = Ew[wi];
        int t = (wi << 6) + lane;
        unsigned long long ile = (lane == 63) ? ~0ull : ((1ull << (lane + 1)) - 1ull);
        int cS = wbS[wi] + __popcll(wS2 & ile);
        int cE = wbL[wi] + __popcll(wE2 & ile);
        if (t < NFRAMES) orow[t] = (cS > cE) ? 1 : 0;
    }
}

extern "C" void kernel_launch(void* const* d_in, const int* in_sizes, int n_in,
                              void* d_out, int out_size, void* d_ws, size_t ws_size,
                              hipStream_t stream) {
    const float* wav = (const float*)d_in[0];
    int* out = (int*)d_out;
    double* bs = (double*)d_ws;   // NBATCH*NBLOCKS doubles = 960 KB

    vad_block_sums<<<(NBATCH * NSAMP) / 4096, 256, 0, stream>>>(wav, bs);
    vad_finish<<<NBATCH, NT, 0, stream>>>(bs, out);
}